// Round 4
// baseline (427.913 us; speedup 1.0000x reference)
//
#include <hip/hip_runtime.h>
#include <math.h>

// EdgeEmbedding: pos[2048,3] f32 -> (dist_edge[N,N,20], dir_edge[N,N,3], mask[N,N]) f32 flat in d_out.
// R3 lesson: hipMemsetAsync graph node runs ~3 TB/s (SDMA/blit path?), not the 6.28 TB/s
// fillBufferAligned rate. Replace with our own grid-stride float4 fill kernel (fill-kernel
// structure: few waves, ~3 VALU per 16B store), then the sparse edge scan (~0.8% density).

#define NATOMS 2048
#define NBASIS 20
#define RCUT   5.0f

__global__ __launch_bounds__(256) void zero_fill_kernel(float4* __restrict__ out, int nquads)
{
    const int stride = gridDim.x * blockDim.x;
    const float4 z = make_float4(0.0f, 0.0f, 0.0f, 0.0f);
    for (int g = blockIdx.x * blockDim.x + threadIdx.x; g < nquads; g += stride)
        out[g] = z;
}

__global__ __launch_bounds__(256) void edge_scan_kernel(
    const float* __restrict__ pos, float* __restrict__ out)
{
    const int t = threadIdx.x;
    const int i = blockIdx.x >> 3;               // 8 blocks of 256 per row -> i block-uniform
    const int j = ((blockIdx.x & 7) << 8) | t;

    const float xi = pos[3 * i + 0], yi = pos[3 * i + 1], zi = pos[3 * i + 2];
    const float xj = pos[3 * j + 0], yj = pos[3 * j + 1], zj = pos[3 * j + 2];
    const float dx = xi - xj, dy = yi - yj, dz = zi - zj;
    float d2;
    {
        // match numpy's unfused mul-then-add rounding so the dist<r mask can't flip at the edge
#pragma clang fp contract(off)
        d2 = (dx * dx + dy * dy) + dz * dz;
    }
    const float dist = sqrtf(d2);
    if (!((dist < RCUT) && (i != j))) return;    // ~99.2% of lanes exit here

    // ---- active edge: ~34K of 4.19M pairs ----
    const float x  = dist * (1.0f / RCUT);
    const float x2 = x * x, x4 = x2 * x2, x8 = x4 * x4, x9 = x8 * x;
    // PolynomialCutoff p=9: 1 - 55 x^9 + 99 x^10 - 45 x^11
    const float env = 1.0f - 55.0f * x9 + 99.0f * x9 * x - 45.0f * x9 * x2;
    const float scale = env / x;

    // RadialBessel sin(k*pi*x), k=1..20 via Chebyshev recurrence
    const float theta = 3.14159265358979323846f * x;
    const float s1 = sinf(theta);
    const float twoc = 2.0f * cosf(theta);
    float vals[NBASIS];
    float pm2 = 0.0f, pm1 = s1;
    vals[0] = scale * s1;
#pragma unroll
    for (int k = 1; k < NBASIS; ++k) {
        const float sk = twoc * pm1 - pm2;
        vals[k] = scale * sk;
        pm2 = pm1; pm1 = sk;
    }

    const long long pair = (long long)i * NATOMS + j;
    float4* __restrict__ deq = (float4*)(out + pair * NBASIS);   // 80B stride -> 16B aligned
#pragma unroll
    for (int q = 0; q < 5; ++q)
        deq[q] = make_float4(vals[4 * q + 0], vals[4 * q + 1], vals[4 * q + 2], vals[4 * q + 3]);

    const float inv = 1.0f / dist;
    float* __restrict__ dir = out + (long long)NATOMS * NATOMS * NBASIS + pair * 3;
    dir[0] = dx * inv; dir[1] = dy * inv; dir[2] = dz * inv;
    out[(long long)NATOMS * NATOMS * (NBASIS + 3) + pair] = 1.0f;
}

extern "C" void kernel_launch(void* const* d_in, const int* in_sizes, int n_in,
                              void* d_out, int out_size, void* d_ws, size_t ws_size,
                              hipStream_t stream) {
    const float* pos = (const float*)d_in[0];
    float* out = (float*)d_out;
    // 1) zero 402 MB with our own fill kernel (grid-stride float4, fill-kernel structure)
    const int nquads = out_size / 4;   // 25,165,824 float4s
    zero_fill_kernel<<<dim3(4096), dim3(256), 0, stream>>>((float4*)out, nquads);
    // 2) sparse scan: one thread per pair; only ~0.8% write (~3.3 MB scattered)
    edge_scan_kernel<<<dim3(NATOMS * 8), dim3(256), 0, stream>>>(pos, out);
}

// Round 5
// 397.113 us; speedup vs baseline: 1.0776x; 1.0776x over previous
//
#include <hip/hip_runtime.h>
#include <math.h>

// EdgeEmbedding: pos[2048,3] f32 -> (dist_edge[N,N,20], dir_edge[N,N,3], mask[N,N]) f32 flat in d_out.
// R4 post-mortem: poison = 272us (d_ws, 1.5GiB) + ~66us (d_out) fixed overhead; R2's fused
// dense kernel was likely already ~68us = fill rate. This round: fused dense writer rebuilt
// fill-style (grid-stride, 24 contiguous 16B stores/thread, no extra dispatches) — optimal
// under either decomposition, and discriminates them.

#define NATOMS  2048
#define NBASIS  20
#define RCUT    5.0f
#define NTHREADS (4096 * 256)   // 1,048,576: 20 dist-quad + 3 dir-quad + 1 mask-quad iters, exact

__global__ __launch_bounds__(256) void edge_embed_fused(
    const float* __restrict__ pos, float* __restrict__ out)
{
    const unsigned tid = blockIdx.x * 256u + threadIdx.x;

    // ---------- region A: dist_edge, 20,971,520 float4 quads (quad = pair*5 + q) ----------
    {
        float4* __restrict__ deq = (float4*)out;
        const unsigned nqA = (unsigned)NATOMS * NATOMS * 5u;
#pragma unroll 1
        for (unsigned g = tid; g < nqA; g += NTHREADS) {
            const unsigned pair = __umulhi(g, 0xCCCCCCCDu) >> 2;   // g / 5
            const unsigned q    = g - pair * 5u;
            const unsigned i    = pair >> 11, j = pair & 2047u;
            const float xi = pos[3*i], yi = pos[3*i+1], zi = pos[3*i+2];
            const float xj = pos[3*j], yj = pos[3*j+1], zj = pos[3*j+2];
            const float dx = xi - xj, dy = yi - yj, dz = zi - zj;
            float d2;
            {
#pragma clang fp contract(off)
                d2 = (dx * dx + dy * dy) + dz * dz;   // numpy-exact rounding for the mask
            }
            const float dist = sqrtf(d2);
            float4 v = make_float4(0.f, 0.f, 0.f, 0.f);
            if ((dist < RCUT) && (i != j)) {          // ~10% of wave-iters have >=1 active lane
                const float x  = dist * (1.0f / RCUT);
                const float x2 = x * x, x4 = x2 * x2, x8 = x4 * x4, x9 = x8 * x;
                const float env = 1.0f - 55.0f * x9 + 99.0f * x9 * x - 45.0f * x9 * x2;
                const float scale = env / x;
                const float theta = 3.14159265358979323846f * x;
                const float k0 = (float)(4u * q + 1u);
                const float s0 = sinf(k0 * theta);
                const float s1 = sinf(k0 * theta + theta);
                const float twoc = 2.0f * cosf(theta);
                const float s2 = twoc * s1 - s0;
                const float s3 = twoc * s2 - s1;
                v = make_float4(scale * s0, scale * s1, scale * s2, scale * s3);
            }
            deq[g] = v;
        }
    }

    // ---------- region B: dir_edge, 3,145,728 quads; quad g = floats 4g..4g+3, spans pairs p0,p0+1 ----------
    {
        float4* __restrict__ dirq = (float4*)(out + (size_t)NATOMS * NATOMS * NBASIS);
        const unsigned nqB = (unsigned)NATOMS * NATOMS * 3u / 4u;
#pragma unroll 1
        for (unsigned g = tid; g < nqB; g += NTHREADS) {
            const unsigned f0 = 4u * g;
            const unsigned p0 = __umulhi(f0, 0xAAAAAAABu) >> 1;    // f0 / 3
            const unsigned c0 = f0 - p0 * 3u;
            float o[6];  // components 0..2 of pair p0, then pair p0+1
#pragma unroll
            for (int s = 0; s < 2; ++s) {
                const unsigned p = p0 + (unsigned)s;
                const unsigned i = (p >> 11) & 2047u, j = p & 2047u;
                const float dx = pos[3*i]   - pos[3*j];
                const float dy = pos[3*i+1] - pos[3*j+1];
                const float dz = pos[3*i+2] - pos[3*j+2];
                float d2;
                {
#pragma clang fp contract(off)
                    d2 = (dx * dx + dy * dy) + dz * dz;
                }
                const float dist = sqrtf(d2);
                const bool m = (dist < RCUT) && (i != j);
                const float inv = m ? (1.0f / dist) : 0.0f;
                o[3*s]   = dx * inv;
                o[3*s+1] = dy * inv;
                o[3*s+2] = dz * inv;
            }
            float4 v;
            float* ve = (float*)&v;
#pragma unroll
            for (int e = 0; e < 4; ++e) {
                const unsigned ce = c0 + (unsigned)e;               // 0..5 indexes o[]
                ve[e] = (ce == 0) ? o[0] : (ce == 1) ? o[1] : (ce == 2) ? o[2]
                       : (ce == 3) ? o[3] : (ce == 4) ? o[4] : o[5];
            }
            dirq[g] = v;
        }
    }

    // ---------- region C: mask, 1,048,576 quads; quad g = pairs 4g..4g+3 (always same row i) ----------
    {
        float4* __restrict__ mq = (float4*)(out + (size_t)NATOMS * NATOMS * (NBASIS + 3));
        const unsigned nqC = (unsigned)NATOMS * NATOMS / 4u;
#pragma unroll 1
        for (unsigned g = tid; g < nqC; g += NTHREADS) {
            const unsigned p0 = 4u * g;
            const unsigned i = p0 >> 11, j0 = p0 & 2047u;
            const float xi = pos[3*i], yi = pos[3*i+1], zi = pos[3*i+2];
            float4 v;
            float* ve = (float*)&v;
#pragma unroll
            for (int e = 0; e < 4; ++e) {
                const unsigned j = j0 + (unsigned)e;
                const float dx = xi - pos[3*j], dy = yi - pos[3*j+1], dz = zi - pos[3*j+2];
                float d2;
                {
#pragma clang fp contract(off)
                    d2 = (dx * dx + dy * dy) + dz * dz;
                }
                const float dist = sqrtf(d2);
                ve[e] = ((dist < RCUT) && (i != j)) ? 1.0f : 0.0f;
            }
            mq[g] = v;
        }
    }
}

extern "C" void kernel_launch(void* const* d_in, const int* in_sizes, int n_in,
                              void* d_out, int out_size, void* d_ws, size_t ws_size,
                              hipStream_t stream) {
    const float* pos = (const float*)d_in[0];
    float* out = (float*)d_out;
    // single dispatch: 4096 wgs x 256 threads, every thread stores 24 x 16B (384 B), 402 MB total
    edge_embed_fused<<<dim3(4096), dim3(256), 0, stream>>>(pos, out);
}